// Round 1
// baseline (428.417 us; speedup 1.0000x reference)
//
#include <hip/hip_runtime.h>
#include <hip/hip_bf16.h>

#define N_NODES 8192
#define E_EDGES 262144
#define IN_DIM  512
#define HID_DIM 256
#define Z_DIM   64

typedef float f32x4  __attribute__((ext_vector_type(4)));
typedef float f32x16 __attribute__((ext_vector_type(16)));
typedef short s16x8  __attribute__((ext_vector_type(8)));

// ---------------------------------------------------------------- row_ptr
// edge_row is sorted; row_ptr[i] = lower_bound(edge_row, i)
__global__ __launch_bounds__(256) void build_rowptr(const int* __restrict__ edge_row,
                                                    int* __restrict__ row_ptr) {
    int i = blockIdx.x * blockDim.x + threadIdx.x;
    if (i > N_NODES) return;
    int lo = 0, hi = E_EDGES;
    while (lo < hi) {
        int mid = (lo + hi) >> 1;
        if (edge_row[mid] < i) lo = mid + 1; else hi = mid;
    }
    row_ptr[i] = lo;
}

// ---------------------------------------------------------------- fp32 GEMM
// C[M,N] = A[M,K] @ B[K,N], row-major, BM=BN=64, BK=16, 256 thr, 4x4/thread.
template <int BM, int BN, int BK>
__global__ __launch_bounds__(256) void gemm_f32(const float* __restrict__ A,
                                                const float* __restrict__ B,
                                                float* __restrict__ C,
                                                int M, int N, int K) {
    __shared__ float As[BK][BM + 4];   // +4 pad keeps 16B alignment, breaks bank stride
    __shared__ float Bs[BK][BN];
    const int tid = threadIdx.x;
    const int tx = tid % (BN / 4);     // 16
    const int ty = tid / (BN / 4);     // 16
    const int m0 = blockIdx.y * BM;
    const int n0 = blockIdx.x * BN;

    f32x4 acc[4];
    #pragma unroll
    for (int i = 0; i < 4; i++) acc[i] = 0.f;

    for (int k0 = 0; k0 < K; k0 += BK) {
        // A tile: 64 rows x 16 k; 4 threads x float4 per row (64B contiguous)
        {
            int m  = tid / (BK / 4);
            int k4 = (tid % (BK / 4)) * 4;
            f32x4 v = *(const f32x4*)(A + (size_t)(m0 + m) * K + k0 + k4);
            As[k4 + 0][m] = v.x;
            As[k4 + 1][m] = v.y;
            As[k4 + 2][m] = v.z;
            As[k4 + 3][m] = v.w;
        }
        // B tile: 16 rows x 64 n; 16 threads x float4 per row
        {
            int k  = tid / 16;
            int n4 = (tid % 16) * 4;
            *(f32x4*)&Bs[k][n4] = *(const f32x4*)(B + (size_t)(k0 + k) * N + n0 + n4);
        }
        __syncthreads();
        #pragma unroll
        for (int k = 0; k < BK; k++) {
            f32x4 a = *(const f32x4*)&As[k][ty * 4];
            f32x4 b = *(const f32x4*)&Bs[k][tx * 4];
            #pragma unroll
            for (int i = 0; i < 4; i++) {
                acc[i].x += a[i] * b.x;
                acc[i].y += a[i] * b.y;
                acc[i].z += a[i] * b.z;
                acc[i].w += a[i] * b.w;
            }
        }
        __syncthreads();
    }
    #pragma unroll
    for (int i = 0; i < 4; i++)
        *(f32x4*)(C + (size_t)(m0 + ty * 4 + i) * N + n0 + tx * 4) = acc[i];
}

// ---------------------------------------------------------------- SPMM1 + relu
// h[row][d] = relu( sum_e w[e]*support[col[e]][d] ); one block (256 thr) per row,
// thread d handles dim d. Per-edge read = 1KB fully coalesced.
__global__ __launch_bounds__(256) void spmm1_relu(const float* __restrict__ support,
                                                  const int* __restrict__ row_ptr,
                                                  const int* __restrict__ edge_col,
                                                  const float* __restrict__ edge_weight,
                                                  float* __restrict__ h) {
    const int row = blockIdx.x;
    const int d   = threadIdx.x;          // 0..255 == HID_DIM
    const int s = row_ptr[row], e = row_ptr[row + 1];
    float acc = 0.f;
    for (int i = s; i < e; i++) {
        int   c = edge_col[i];
        float w = edge_weight[i];
        acc += w * support[(size_t)c * HID_DIM + d];
    }
    h[(size_t)row * HID_DIM + d] = fmaxf(acc, 0.f);
}

// ---------------------------------------------------------------- SPMM2
// z[row][d] = sum_e w[e]*zpre[col[e]][d]; one wave (64 lanes == Z_DIM) per row.
// Writes fp32 z to d_out and bf16 copy for the MFMA recon kernel.
__global__ __launch_bounds__(256) void spmm2(const float* __restrict__ zpre,
                                             const int* __restrict__ row_ptr,
                                             const int* __restrict__ edge_col,
                                             const float* __restrict__ edge_weight,
                                             float* __restrict__ z_out,
                                             __hip_bfloat16* __restrict__ zb) {
    const int wave = threadIdx.x >> 6;
    const int lane = threadIdx.x & 63;
    const int row  = blockIdx.x * 4 + wave;
    const int s = row_ptr[row], e = row_ptr[row + 1];
    float acc = 0.f;
    for (int i = s; i < e; i++)
        acc += edge_weight[i] * zpre[(size_t)edge_col[i] * Z_DIM + lane];
    z_out[(size_t)row * Z_DIM + lane] = acc;
    zb[(size_t)row * Z_DIM + lane]    = __float2bfloat16(acc);
}

// ---------------------------------------------------------------- recon = z @ z^T
// bf16 MFMA 32x32x16. Block = 128x128 tile, 4 waves (2x2), each wave 64x64
// as 2x2 of 32x32 accumulators. K=64 -> 4 k-steps.
// A frag: lane holds z[R+m][8*(lane>>5)+j], m=lane&31  (8 contiguous bf16 = 16B)
// B frag: lane holds z[C+n][8*(lane>>5)+j], n=lane&31  (z@z^T => B loads like A)
// C/D   : col=lane&31, row=(reg&3)+8*(reg>>2)+4*(lane>>5)   [measured m74/m101]
__global__ __launch_bounds__(256) void recon_mfma(const __hip_bfloat16* __restrict__ zb,
                                                  float* __restrict__ recon) {
    const int wave = threadIdx.x >> 6;
    const int lane = threadIdx.x & 63;
    const int wr = wave >> 1, wc = wave & 1;
    const int R = blockIdx.y * 128 + wr * 64;
    const int C = blockIdx.x * 128 + wc * 64;
    const int l31 = lane & 31;
    const int lhi = lane >> 5;
    const short* zs = (const short*)zb;

    f32x16 acc[2][2];
    #pragma unroll
    for (int i = 0; i < 2; i++)
        #pragma unroll
        for (int j = 0; j < 2; j++) acc[i][j] = 0.f;

    #pragma unroll
    for (int s = 0; s < 4; s++) {
        s16x8 a[2], b[2];
        #pragma unroll
        for (int i = 0; i < 2; i++) {
            a[i] = *(const s16x8*)(zs + (size_t)(R + i * 32 + l31) * Z_DIM + s * 16 + 8 * lhi);
            b[i] = *(const s16x8*)(zs + (size_t)(C + i * 32 + l31) * Z_DIM + s * 16 + 8 * lhi);
        }
        #pragma unroll
        for (int i = 0; i < 2; i++)
            #pragma unroll
            for (int j = 0; j < 2; j++)
                acc[i][j] = __builtin_amdgcn_mfma_f32_32x32x16_bf16(a[i], b[j], acc[i][j], 0, 0, 0);
    }

    #pragma unroll
    for (int i = 0; i < 2; i++)
        #pragma unroll
        for (int j = 0; j < 2; j++)
            #pragma unroll
            for (int r = 0; r < 16; r++) {
                int m   = (r & 3) + 8 * (r >> 2) + 4 * lhi;
                int row = R + i * 32 + m;
                int col = C + j * 32 + l31;
                recon[(size_t)row * N_NODES + col] = acc[i][j][r];
            }
}

// ---------------------------------------------------------------- launch
extern "C" void kernel_launch(void* const* d_in, const int* in_sizes, int n_in,
                              void* d_out, int out_size, void* d_ws, size_t ws_size,
                              hipStream_t stream) {
    const float* x           = (const float*)d_in[0];
    const float* w1          = (const float*)d_in[1];
    const float* w2          = (const float*)d_in[2];
    const int*   edge_row    = (const int*)d_in[3];
    const int*   edge_col    = (const int*)d_in[4];
    const float* edge_weight = (const float*)d_in[5];

    float* recon = (float*)d_out;                                   // [N, N]
    float* z_out = recon + (size_t)N_NODES * N_NODES;               // [N, Z_DIM]

    // workspace layout
    float* support = (float*)d_ws;                                  // [N, HID_DIM] 8 MB
    float* h       = support + (size_t)N_NODES * HID_DIM;           // [N, HID_DIM] 8 MB
    float* zpre    = h + (size_t)N_NODES * HID_DIM;                 // [N, Z_DIM]   2 MB
    __hip_bfloat16* zb = (__hip_bfloat16*)(zpre + (size_t)N_NODES * Z_DIM); // 1 MB
    int*   row_ptr = (int*)(zb + (size_t)N_NODES * Z_DIM);          // [N+1]

    build_rowptr<<<(N_NODES + 256) / 256, 256, 0, stream>>>(edge_row, row_ptr);

    gemm_f32<64, 64, 16><<<dim3(HID_DIM / 64, N_NODES / 64), 256, 0, stream>>>(
        x, w1, support, N_NODES, HID_DIM, IN_DIM);

    spmm1_relu<<<N_NODES, 256, 0, stream>>>(support, row_ptr, edge_col, edge_weight, h);

    gemm_f32<64, 64, 16><<<dim3(Z_DIM / 64, N_NODES / 64), 256, 0, stream>>>(
        h, w2, zpre, N_NODES, Z_DIM, HID_DIM);

    spmm2<<<N_NODES / 4, 256, 0, stream>>>(zpre, row_ptr, edge_col, edge_weight, z_out, zb);

    recon_mfma<<<dim3(N_NODES / 128, N_NODES / 128), 256, 0, stream>>>(zb, recon);
}

// Round 2
// 392.769 us; speedup vs baseline: 1.0908x; 1.0908x over previous
//
#include <hip/hip_runtime.h>
#include <hip/hip_bf16.h>

#define N_NODES 8192
#define E_EDGES 262144
#define IN_DIM  512
#define HID_DIM 256
#define Z_DIM   64

typedef float f32x4  __attribute__((ext_vector_type(4)));
typedef float f32x16 __attribute__((ext_vector_type(16)));
typedef short s16x4  __attribute__((ext_vector_type(4)));
typedef short s16x8  __attribute__((ext_vector_type(8)));

static __device__ __forceinline__ short bf16_bits(float f) {
    __hip_bfloat16 b = __float2bfloat16(f);
    return *reinterpret_cast<short*>(&b);
}
static __device__ __forceinline__ float bits_to_f32(short s) {
    __hip_bfloat16 b = *reinterpret_cast<__hip_bfloat16*>(&s);
    return __bfloat162float(b);
}

// ---------------------------------------------------------------- row_ptr
__global__ __launch_bounds__(256) void build_rowptr(const int* __restrict__ edge_row,
                                                    int* __restrict__ row_ptr) {
    int i = blockIdx.x * blockDim.x + threadIdx.x;
    if (i > N_NODES) return;
    int lo = 0, hi = E_EDGES;
    while (lo < hi) {
        int mid = (lo + hi) >> 1;
        if (edge_row[mid] < i) lo = mid + 1; else hi = mid;
    }
    row_ptr[i] = lo;
}

// ---------------------------------------------------------------- split x -> bf16 hi/lo
// x[8192][512] f32 -> xhi, xlo bf16 (Ozaki split: x ~= hi + lo, residual ~2^-18)
__global__ __launch_bounds__(256) void split_x(const float* __restrict__ x,
                                               short* __restrict__ xhi,
                                               short* __restrict__ xlo) {
    size_t gid = (size_t)blockIdx.x * 256 + threadIdx.x;
    f32x4 v = *(const f32x4*)(x + gid * 4);
    s16x4 h, l;
    #pragma unroll
    for (int j = 0; j < 4; j++) {
        short hb = bf16_bits(v[j]);
        h[j] = hb;
        l[j] = bf16_bits(v[j] - bits_to_f32(hb));
    }
    *(s16x4*)(xhi + gid * 4) = h;
    *(s16x4*)(xlo + gid * 4) = l;
}

// ---------------------------------------------------------------- w1 -> transposed split
// w1[512][256] -> w1t_hi/lo[256][512] bf16 (so B-fragments read contiguous k)
__global__ __launch_bounds__(256) void split_w1t(const float* __restrict__ w1,
                                                 short* __restrict__ w1t_hi,
                                                 short* __restrict__ w1t_lo) {
    int id = blockIdx.x * 256 + threadIdx.x;        // 0 .. 512*256-1
    int k = id / HID_DIM, n = id % HID_DIM;
    float v = w1[id];
    short hb = bf16_bits(v);
    w1t_hi[(size_t)n * IN_DIM + k] = hb;
    w1t_lo[(size_t)n * IN_DIM + k] = bf16_bits(v - bits_to_f32(hb));
}

// ---------------------------------------------------------------- gemm1: support = x @ w1
// Split-bf16 MFMA 32x32x16, 3 products (Ah*Bh + Al*Bh + Ah*Bl), fp32 accum.
// Block = 4 waves in 2x2, each wave one 32x32 tile; block tile 64x64.
__global__ __launch_bounds__(256) void gemm1_mfma(const short* __restrict__ xhi,
                                                  const short* __restrict__ xlo,
                                                  const short* __restrict__ bhi,
                                                  const short* __restrict__ blo,
                                                  float* __restrict__ support) {
    const int wave = threadIdx.x >> 6, lane = threadIdx.x & 63;
    const int wr = wave >> 1, wc = wave & 1;
    const int R = blockIdx.y * 64 + wr * 32;
    const int C = blockIdx.x * 64 + wc * 32;
    const int l31 = lane & 31, lhi = lane >> 5;

    const size_t arow = (size_t)(R + l31) * IN_DIM + 8 * lhi;
    const size_t brow = (size_t)(C + l31) * IN_DIM + 8 * lhi;

    f32x16 acc = 0.f;
    #pragma unroll 4
    for (int k0 = 0; k0 < IN_DIM; k0 += 16) {
        s16x8 ah = *(const s16x8*)(xhi + arow + k0);
        s16x8 al = *(const s16x8*)(xlo + arow + k0);
        s16x8 bh = *(const s16x8*)(bhi + brow + k0);
        s16x8 bl = *(const s16x8*)(blo + brow + k0);
        acc = __builtin_amdgcn_mfma_f32_32x32x16_bf16(ah, bh, acc, 0, 0, 0);
        acc = __builtin_amdgcn_mfma_f32_32x32x16_bf16(al, bh, acc, 0, 0, 0);
        acc = __builtin_amdgcn_mfma_f32_32x32x16_bf16(ah, bl, acc, 0, 0, 0);
    }
    #pragma unroll
    for (int r = 0; r < 16; r++) {
        int m = (r & 3) + 8 * (r >> 2) + 4 * lhi;
        support[(size_t)(R + m) * HID_DIM + C + l31] = acc[r];
    }
}

// ---------------------------------------------------------------- fp32 GEMM (for h@w2)
template <int BM, int BN, int BK>
__global__ __launch_bounds__(256) void gemm_f32(const float* __restrict__ A,
                                                const float* __restrict__ B,
                                                float* __restrict__ C,
                                                int M, int N, int K) {
    __shared__ float As[BK][BM + 4];
    __shared__ float Bs[BK][BN];
    const int tid = threadIdx.x;
    const int tx = tid % (BN / 4);
    const int ty = tid / (BN / 4);
    const int m0 = blockIdx.y * BM;
    const int n0 = blockIdx.x * BN;

    f32x4 acc[4];
    #pragma unroll
    for (int i = 0; i < 4; i++) acc[i] = 0.f;

    for (int k0 = 0; k0 < K; k0 += BK) {
        {
            int m  = tid / (BK / 4);
            int k4 = (tid % (BK / 4)) * 4;
            f32x4 v = *(const f32x4*)(A + (size_t)(m0 + m) * K + k0 + k4);
            As[k4 + 0][m] = v.x;
            As[k4 + 1][m] = v.y;
            As[k4 + 2][m] = v.z;
            As[k4 + 3][m] = v.w;
        }
        {
            int k  = tid / 16;
            int n4 = (tid % 16) * 4;
            *(f32x4*)&Bs[k][n4] = *(const f32x4*)(B + (size_t)(k0 + k) * N + n0 + n4);
        }
        __syncthreads();
        #pragma unroll
        for (int k = 0; k < BK; k++) {
            f32x4 a = *(const f32x4*)&As[k][ty * 4];
            f32x4 b = *(const f32x4*)&Bs[k][tx * 4];
            #pragma unroll
            for (int i = 0; i < 4; i++) {
                acc[i].x += a[i] * b.x;
                acc[i].y += a[i] * b.y;
                acc[i].z += a[i] * b.z;
                acc[i].w += a[i] * b.w;
            }
        }
        __syncthreads();
    }
    #pragma unroll
    for (int i = 0; i < 4; i++)
        *(f32x4*)(C + (size_t)(m0 + ty * 4 + i) * N + n0 + tx * 4) = acc[i];
}

// ---------------------------------------------------------------- SPMM1 + relu
// One wave per row; lane covers dims 4*lane..4*lane+3 (f32x4 gather = 1KB/instr).
// Edge loop unrolled x4 so 4 gathers are in flight.
__global__ __launch_bounds__(256) void spmm1_relu(const float* __restrict__ support,
                                                  const int* __restrict__ row_ptr,
                                                  const int* __restrict__ edge_col,
                                                  const float* __restrict__ edge_weight,
                                                  float* __restrict__ h) {
    const int wave = threadIdx.x >> 6, lane = threadIdx.x & 63;
    const int row = blockIdx.x * 4 + wave;
    const int s = row_ptr[row], e = row_ptr[row + 1];
    const int d = lane * 4;
    f32x4 acc = 0.f;
    int i = s;
    for (; i + 4 <= e; i += 4) {
        int   c0 = edge_col[i],     c1 = edge_col[i + 1];
        int   c2 = edge_col[i + 2], c3 = edge_col[i + 3];
        float w0 = edge_weight[i],     w1 = edge_weight[i + 1];
        float w2 = edge_weight[i + 2], w3 = edge_weight[i + 3];
        f32x4 v0 = *(const f32x4*)(support + (size_t)c0 * HID_DIM + d);
        f32x4 v1 = *(const f32x4*)(support + (size_t)c1 * HID_DIM + d);
        f32x4 v2 = *(const f32x4*)(support + (size_t)c2 * HID_DIM + d);
        f32x4 v3 = *(const f32x4*)(support + (size_t)c3 * HID_DIM + d);
        #pragma unroll
        for (int j = 0; j < 4; j++)
            acc[j] = fmaf(w0, v0[j], fmaf(w1, v1[j], fmaf(w2, v2[j], fmaf(w3, v3[j], acc[j]))));
    }
    for (; i < e; i++) {
        int   c = edge_col[i];
        float w = edge_weight[i];
        f32x4 v = *(const f32x4*)(support + (size_t)c * HID_DIM + d);
        #pragma unroll
        for (int j = 0; j < 4; j++) acc[j] = fmaf(w, v[j], acc[j]);
    }
    f32x4 r;
    #pragma unroll
    for (int j = 0; j < 4; j++) r[j] = fmaxf(acc[j], 0.f);
    *(f32x4*)(h + (size_t)row * HID_DIM + d) = r;
}

// ---------------------------------------------------------------- SPMM2
// One wave per row, lane = dim (Z_DIM=64); edge loop unrolled x4.
__global__ __launch_bounds__(256) void spmm2(const float* __restrict__ zpre,
                                             const int* __restrict__ row_ptr,
                                             const int* __restrict__ edge_col,
                                             const float* __restrict__ edge_weight,
                                             float* __restrict__ z_out,
                                             __hip_bfloat16* __restrict__ zb) {
    const int wave = threadIdx.x >> 6, lane = threadIdx.x & 63;
    const int row = blockIdx.x * 4 + wave;
    const int s = row_ptr[row], e = row_ptr[row + 1];
    float acc = 0.f;
    int i = s;
    for (; i + 4 <= e; i += 4) {
        int   c0 = edge_col[i],     c1 = edge_col[i + 1];
        int   c2 = edge_col[i + 2], c3 = edge_col[i + 3];
        float w0 = edge_weight[i],     w1 = edge_weight[i + 1];
        float w2 = edge_weight[i + 2], w3 = edge_weight[i + 3];
        float v0 = zpre[(size_t)c0 * Z_DIM + lane];
        float v1 = zpre[(size_t)c1 * Z_DIM + lane];
        float v2 = zpre[(size_t)c2 * Z_DIM + lane];
        float v3 = zpre[(size_t)c3 * Z_DIM + lane];
        acc = fmaf(w0, v0, fmaf(w1, v1, fmaf(w2, v2, fmaf(w3, v3, acc))));
    }
    for (; i < e; i++)
        acc = fmaf(edge_weight[i], zpre[(size_t)edge_col[i] * Z_DIM + lane], acc);
    z_out[(size_t)row * Z_DIM + lane] = acc;
    zb[(size_t)row * Z_DIM + lane]    = __float2bfloat16(acc);
}

// ---------------------------------------------------------------- recon = z @ z^T
__global__ __launch_bounds__(256) void recon_mfma(const __hip_bfloat16* __restrict__ zb,
                                                  float* __restrict__ recon) {
    const int wave = threadIdx.x >> 6;
    const int lane = threadIdx.x & 63;
    const int wr = wave >> 1, wc = wave & 1;
    const int R = blockIdx.y * 128 + wr * 64;
    const int C = blockIdx.x * 128 + wc * 64;
    const int l31 = lane & 31;
    const int lhi = lane >> 5;
    const short* zs = (const short*)zb;

    f32x16 acc[2][2];
    #pragma unroll
    for (int i = 0; i < 2; i++)
        #pragma unroll
        for (int j = 0; j < 2; j++) acc[i][j] = 0.f;

    #pragma unroll
    for (int s = 0; s < 4; s++) {
        s16x8 a[2], b[2];
        #pragma unroll
        for (int i = 0; i < 2; i++) {
            a[i] = *(const s16x8*)(zs + (size_t)(R + i * 32 + l31) * Z_DIM + s * 16 + 8 * lhi);
            b[i] = *(const s16x8*)(zs + (size_t)(C + i * 32 + l31) * Z_DIM + s * 16 + 8 * lhi);
        }
        #pragma unroll
        for (int i = 0; i < 2; i++)
            #pragma unroll
            for (int j = 0; j < 2; j++)
                acc[i][j] = __builtin_amdgcn_mfma_f32_32x32x16_bf16(a[i], b[j], acc[i][j], 0, 0, 0);
    }

    #pragma unroll
    for (int i = 0; i < 2; i++)
        #pragma unroll
        for (int j = 0; j < 2; j++)
            #pragma unroll
            for (int r = 0; r < 16; r++) {
                int m   = (r & 3) + 8 * (r >> 2) + 4 * lhi;
                int row = R + i * 32 + m;
                int col = C + j * 32 + l31;
                recon[(size_t)row * N_NODES + col] = acc[i][j][r];
            }
}

// ---------------------------------------------------------------- launch
extern "C" void kernel_launch(void* const* d_in, const int* in_sizes, int n_in,
                              void* d_out, int out_size, void* d_ws, size_t ws_size,
                              hipStream_t stream) {
    const float* x           = (const float*)d_in[0];
    const float* w1          = (const float*)d_in[1];
    const float* w2          = (const float*)d_in[2];
    const int*   edge_row    = (const int*)d_in[3];
    const int*   edge_col    = (const int*)d_in[4];
    const float* edge_weight = (const float*)d_in[5];

    float* recon = (float*)d_out;                                   // [N, N]
    float* z_out = recon + (size_t)N_NODES * N_NODES;               // [N, Z_DIM]

    // workspace layout
    char* ws = (char*)d_ws;
    short* xhi    = (short*)ws;                          ws += (size_t)N_NODES * IN_DIM * 2;   // 8 MB
    short* xlo    = (short*)ws;                          ws += (size_t)N_NODES * IN_DIM * 2;   // 8 MB
    short* w1t_hi = (short*)ws;                          ws += (size_t)HID_DIM * IN_DIM * 2;   // 256 KB
    short* w1t_lo = (short*)ws;                          ws += (size_t)HID_DIM * IN_DIM * 2;   // 256 KB
    float* support = (float*)ws;                         ws += (size_t)N_NODES * HID_DIM * 4;  // 8 MB
    float* h       = (float*)ws;                         ws += (size_t)N_NODES * HID_DIM * 4;  // 8 MB
    float* zpre    = (float*)ws;                         ws += (size_t)N_NODES * Z_DIM * 4;    // 2 MB
    __hip_bfloat16* zb = (__hip_bfloat16*)ws;            ws += (size_t)N_NODES * Z_DIM * 2;    // 1 MB
    int* row_ptr   = (int*)ws;

    build_rowptr<<<(N_NODES + 256) / 256, 256, 0, stream>>>(edge_row, row_ptr);

    split_x<<<(N_NODES * IN_DIM / 4 + 255) / 256, 256, 0, stream>>>(x, xhi, xlo);
    split_w1t<<<(IN_DIM * HID_DIM + 255) / 256, 256, 0, stream>>>(w1, w1t_hi, w1t_lo);

    gemm1_mfma<<<dim3(HID_DIM / 64, N_NODES / 64), 256, 0, stream>>>(
        xhi, xlo, w1t_hi, w1t_lo, support);

    spmm1_relu<<<N_NODES / 4, 256, 0, stream>>>(support, row_ptr, edge_col, edge_weight, h);

    gemm_f32<64, 64, 16><<<dim3(Z_DIM / 64, N_NODES / 64), 256, 0, stream>>>(
        h, w2, zpre, N_NODES, Z_DIM, HID_DIM);

    spmm2<<<N_NODES / 4, 256, 0, stream>>>(zpre, row_ptr, edge_col, edge_weight, z_out, zb);

    recon_mfma<<<dim3(N_NODES / 128, N_NODES / 128), 256, 0, stream>>>(zb, recon);
}